// Round 6
// baseline (423.942 us; speedup 1.0000x reference)
//
#include <hip/hip_runtime.h>
#include <stdint.h>
#include <stddef.h>

typedef float f32x4 __attribute__((ext_vector_type(4)));
typedef short bf16x8 __attribute__((ext_vector_type(8)));
typedef unsigned short u16;
typedef u16 u16x4 __attribute__((ext_vector_type(4)));
typedef u16 u16x8 __attribute__((ext_vector_type(8)));

#define MFMA16(a,b,c) __builtin_amdgcn_mfma_f32_16x16x32_bf16((a),(b),(c),0,0,0)

__device__ __forceinline__ float bf2f(u16 u){ union{unsigned int i;float f;}v; v.i=((unsigned int)u)<<16; return v.f; }
__device__ __forceinline__ u16 f2bf(float f){ union{float f;unsigned int i;}v; v.f=f; unsigned int x=v.i; return (u16)((x + 0x7FFFu + ((x>>16)&1u))>>16); }

__device__ __forceinline__ void gload_lds16(const void* g, void* l){
  __builtin_amdgcn_global_load_lds((const __attribute__((address_space(1))) void*)g,
                                   (__attribute__((address_space(3))) void*)l, 16, 0, 0);
}

// plain barrier, no scheduler pinning (m141 lesson)
#define BAR() do{ asm volatile("" ::: "memory"); __builtin_amdgcn_s_barrier(); \
                  asm volatile("" ::: "memory"); }while(0)

// ---------------- elementwise ----------------
__global__ void k_convert(const float* __restrict__ src, u16* __restrict__ dst, int n4){
  int stride = gridDim.x * blockDim.x;
  for (int i = blockIdx.x*blockDim.x + threadIdx.x; i < n4; i += stride){
    float4 v = ((const float4*)src)[i];
    u16x4 o; o[0]=f2bf(v.x); o[1]=f2bf(v.y); o[2]=f2bf(v.z); o[3]=f2bf(v.w);
    ((u16x4*)dst)[i] = o;
  }
}

__global__ void k_rope_table(float* __restrict__ ct, float* __restrict__ st){
  int i = blockIdx.x*blockDim.x + threadIdx.x; // 4096*64 exactly
  int s = i >> 6, p = i & 63;
  float freq = 1.0f / powf(10000.0f, (float)(2*p) * (1.0f/128.0f));
  float ang = (float)s * freq;
  ct[i] = cosf(ang); st[i] = sinf(ang);
}

// ---- 8-wave GEMM, BM=256 x BN (192|256), BK=64, 2 phases/K-tile, counted prefetch ----
// C[M,N] = A[M,K] @ Bt[N,K]^T. EPI==1: QKV split epilogue with fused RoPE.
template<int BN, int EPI>
__global__ __launch_bounds__(512, 2) void k_gemm8(
    const u16* __restrict__ A, const u16* __restrict__ Bt,
    float* __restrict__ Cf,
    u16* __restrict__ qb, u16* __restrict__ kb, u16* __restrict__ vtb,
    const float* __restrict__ ct, const float* __restrict__ st,
    int M, int N, int K)
{
  constexpr int NF = BN/64;                 // B frags/wave per kk; also B stage chunks/thread
  constexpr int TILEU = 16384 + BN*64;      // u16 per buffer (A 256x64 + B BNx64)
  extern __shared__ u16 Sdyn[];
  const int tid = threadIdx.x, wid = tid >> 6, lane = tid & 63;
  const int lr = lane & 15, lg = lane >> 4;
  const int wm = wid >> 2, wn = wid & 3;
  const int bm = blockIdx.x * 256, bn = blockIdx.y * BN;
  const int ns = K >> 6;

  // staging source offsets (swizzled col so LDS dest is linear; rule #21)
  size_t aOff[4]; int aDst[4];
  #pragma unroll
  for (int c = 0; c < 4; ++c){
    int ch = tid + c*512, row = ch >> 3, u = ch & 7;
    aOff[c] = (size_t)(bm + row)*K + ((u ^ (row & 7))*8);
    aDst[c] = ch*8;
  }
  size_t bOff[NF]; int bDst[NF];
  #pragma unroll
  for (int c = 0; c < NF; ++c){
    int ch = tid + c*512, row = ch >> 3, u = ch & 7;
    bOff[c] = (size_t)(bn + row)*K + ((u ^ (row & 7))*8);
    bDst[c] = ch*8;
  }

  // fragment read geometry
  const int rA = wm*128 + lr;
  const int rB = wn*(BN/4) + lr;
  const int u0 = ((0 + lg) ^ (lr & 7)) * 8;
  const int u1 = ((4 + lg) ^ (lr & 7)) * 8;

  f32x4 acc[8][NF] = {};

  // prologue: stage tile0 into buf0, drain
  {
    u16* SA0 = Sdyn; u16* SB0 = Sdyn + 16384;
    #pragma unroll
    for (int c = 0; c < 4; ++c)  gload_lds16(A  + aOff[c], SA0 + aDst[c]);
    #pragma unroll
    for (int c = 0; c < NF; ++c) gload_lds16(Bt + bOff[c], SB0 + bDst[c]);
    asm volatile("s_waitcnt vmcnt(0)" ::: "memory");
    BAR();
  }

  for (int t = 0; t < ns; ++t){
    const int buf = t & 1;
    u16* SA  = Sdyn + buf*TILEU;
    u16* SB  = SA + 16384;
    u16* SAn = Sdyn + (buf^1)*TILEU;
    u16* SBn = SAn + 16384;
    const size_t k1 = (size_t)((t+1 < ns) ? t+1 : t) << 6;

    // ---- phase 1: kk0 reads + all t+1 stages ----
    bf16x8 af[8], bq[NF];
    #pragma unroll
    for (int m = 0; m < 8; ++m) af[m] = *(const bf16x8*)(SA + (rA + m*16)*64 + u0);
    #pragma unroll
    for (int n = 0; n < NF; ++n) bq[n] = *(const bf16x8*)(SB + (rB + n*16)*64 + u0);
    #pragma unroll
    for (int c = 0; c < 4; ++c)  gload_lds16(A  + aOff[c] + k1, SAn + aDst[c]);
    #pragma unroll
    for (int c = 0; c < NF; ++c) gload_lds16(Bt + bOff[c] + k1, SBn + bDst[c]);
    BAR();
    __builtin_amdgcn_s_setprio(1);
    #pragma unroll
    for (int m = 0; m < 8; ++m)
      #pragma unroll
      for (int n = 0; n < NF; ++n)
        acc[m][n] = MFMA16(af[m], bq[n], acc[m][n]);
    __builtin_amdgcn_s_setprio(0);
    BAR();

    // ---- phase 2: kk1 reads ----
    #pragma unroll
    for (int m = 0; m < 8; ++m) af[m] = *(const bf16x8*)(SA + (rA + m*16)*64 + u1);
    #pragma unroll
    for (int n = 0; n < NF; ++n) bq[n] = *(const bf16x8*)(SB + (rB + n*16)*64 + u1);
    BAR();
    __builtin_amdgcn_s_setprio(1);
    #pragma unroll
    for (int m = 0; m < 8; ++m)
      #pragma unroll
      for (int n = 0; n < NF; ++n)
        acc[m][n] = MFMA16(af[m], bq[n], acc[m][n]);
    __builtin_amdgcn_s_setprio(0);
    asm volatile("s_waitcnt vmcnt(0)" ::: "memory");   // t+1 landed (issued 1.5 phases ago)
    BAR();
  }

  // ---- epilogue ----
  #pragma unroll
  for (int m = 0; m < 8; ++m){
    int mrow = bm + wm*128 + m*16 + lg*4;
    #pragma unroll
    for (int n = 0; n < NF; ++n){
      int ncol = bn + wn*(BN/4) + n*16 + lr;
      f32x4 v = acc[m][n];
      if (EPI == 0){
        #pragma unroll
        for (int r = 0; r < 4; ++r)
          Cf[(size_t)(mrow + r)*N + ncol] = v[r];
      } else {
        if (ncol < 2560){
          // Q or K: fused RoPE. Pair partner sits in lane lr^1 (adjacent col).
          const int p = (ncol & 127) >> 1;
          const bool odd = (lr & 1);
          #pragma unroll
          for (int r = 0; r < 4; ++r){
            float pr = __shfl_xor(v[r], 1);
            int srow = (mrow + r) & 4095;
            float cs = ct[(size_t)srow*64 + p];
            float sn = st[(size_t)srow*64 + p];
            float out = odd ? (pr*sn + v[r]*cs) : (v[r]*cs - pr*sn);
            if (ncol < 2048) qb[(size_t)(mrow + r)*2048 + ncol] = f2bf(out);
            else             kb[(size_t)(mrow + r)*512 + (ncol - 2048)] = f2bf(out);
          }
        } else {                               // V transposed: ((b*4+hk)*128+d, 4096)
          int np = ncol - 2560, hkk = np >> 7, d = np & 127;
          int bb2 = mrow >> 12, sl = mrow & 4095;
          u16x4 pk;
          #pragma unroll
          for (int r = 0; r < 4; ++r) pk[r] = f2bf(v[r]);
          *(u16x4*)(vtb + ((size_t)((bb2*4 + hkk)*128 + d))*4096 + sl) = pk;
        }
      }
    }
  }
}

// ---------------- attention: 8 waves x 16 q-rows = 128 rows/block ----------------
__global__ __launch_bounds__(512, 4) void k_attn(
    const u16* __restrict__ qb, const u16* __restrict__ kb,
    const u16* __restrict__ vtb, u16* __restrict__ ob)
{
  __shared__ u16 Ks[64*128];    // [key 64][dim 128], 16B-chunk XOR(row&7) swizzle
  __shared__ u16 Vs[128*64];    // [dim 128][key 64], 16B-chunk XOR(row&7) swizzle
  __shared__ u16 Ps[8][16*64];  // per-wave P: [qrow 16][key 64], XOR(row&7) swizzle

  const int bid0 = blockIdx.x;
  const int bid = (bid0 & 7)*128 + (bid0 >> 3);     // bijective XCD swizzle (1024 = 8*128)
  const int qblk = bid & 31, h = (bid >> 5) & 15, b = bid >> 9;
  const int hk = h >> 2;
  const int tid = threadIdx.x, wid = tid >> 6, lane = tid & 63;
  const int lr = lane & 15, lg = lane >> 4;
  const int q0 = qblk*128;
  const int qw = q0 + wid*16;

  bf16x8 qf[4];
  {
    const u16* qp = qb + (size_t)(b*4096 + qw + lr)*2048 + h*128;
    #pragma unroll
    for (int ks = 0; ks < 4; ++ks)
      qf[ks] = *(const bf16x8*)(qp + ks*32 + lg*8);
  }

  const int sA = wid*64 + lane;
  const int krA = sA >> 4, kcA = sA & 15;
  const int krB = krA + 32;
  const int vrA = sA >> 3, vcA = sA & 7;
  const int vrB = vrA + 64;
  const u16* kSrcA = kb + (size_t)(b*4096 + krA)*512 + hk*128 + ((kcA ^ (krA & 7))*8);
  const u16* kSrcB = kb + (size_t)(b*4096 + krB)*512 + hk*128 + ((kcA ^ (krB & 7))*8);
  const u16* vSrcA = vtb + ((size_t)(b*4 + hk)*128 + vrA)*4096 + ((vcA ^ (vrA & 7))*8);
  const u16* vSrcB = vtb + ((size_t)(b*4 + hk)*128 + vrB)*4096 + ((vcA ^ (vrB & 7))*8);
  u16* const ldsKA = Ks + sA*8;
  u16* const ldsKB = Ks + (sA + 512)*8;
  u16* const ldsVA = Vs + sA*8;
  u16* const ldsVB = Vs + (sA + 512)*8;

  u16* Pw = (u16*)Ps[wid];

  f32x4 o[8] = {};
  float lst = 0.f;

  const int kt0 = (q0 >= 512) ? (q0 - 512) : 0;
  const int ktend = q0 + 128;

  for (int kt = kt0; kt < ktend; kt += 64){
    __syncthreads();
    gload_lds16(kSrcA + (size_t)kt*512, ldsKA);
    gload_lds16(kSrcB + (size_t)kt*512, ldsKB);
    gload_lds16(vSrcA + kt, ldsVA);
    gload_lds16(vSrcB + kt, ldsVB);
    __syncthreads();

    if (kt > qw + 15 || kt + 63 < qw - 512) continue;

    f32x4 sc[4] = {};
    #pragma unroll
    for (int ks = 0; ks < 4; ++ks){
      #pragma unroll
      for (int nt = 0; nt < 4; ++nt){
        int krow = nt*16 + lr;
        bf16x8 kf = *(const bf16x8*)&Ks[krow*128 + (((ks*4 + lg) ^ (krow & 7)))*8];
        sc[nt] = MFMA16(kf, qf[ks], sc[nt]);
      }
    }

    {
      int dql = (qw + lr) - kt - lg*4;
      float ps = 0.f;
      #pragma unroll
      for (int nt = 0; nt < 4; ++nt){
        unsigned int pk[2];
        #pragma unroll
        for (int j = 0; j < 2; ++j){
          unsigned int w2[2];
          #pragma unroll
          for (int rr = 0; rr < 2; ++rr){
            const int r = j*2 + rr;
            float a = sc[nt][r] * 0.00441941738f;
            a = fminf(fmaxf(a, -0.55f), 0.55f);
            float a2 = a*a;
            float hp = __builtin_fmaf(a2, 0.13333333f, -0.33333333f);
            hp = __builtin_fmaf(a2, hp, 1.0f);
            float t = a * hp;
            float g = (t - 1.0f) * 28.853901f;
            float p = __builtin_amdgcn_exp2f(g);
            int diff = dql - (nt*16 + r);
            p = ((unsigned)diff <= 512u) ? p : 0.f;
            ps += p;
            union{float f; unsigned int u;} cv; cv.f = p;
            w2[rr] = cv.u + 0x8000u;
          }
          pk[j] = (w2[0] >> 16) | (w2[1] & 0xffff0000u);
        }
        const int row = lr;
        const int bytecol = nt*32 + lg*8;
        const int c16 = bytecol >> 4;
        char* basep = (char*)Pw + row*128 + (((c16 ^ (row & 7)) << 4)) + (bytecol & 15);
        *(unsigned int*)(basep)     = pk[0];
        *(unsigned int*)(basep + 4) = pk[1];
      }
      lst += ps;
    }

    __builtin_amdgcn_s_waitcnt(0xC07F);
    __builtin_amdgcn_sched_barrier(0);

    #pragma unroll
    for (int kk = 0; kk < 2; ++kk){
      bf16x8 pa = *(const bf16x8*)((char*)Pw + lr*128 + (((kk*4+lg) ^ (lr & 7)) << 4));
      #pragma unroll
      for (int dt = 0; dt < 8; ++dt){
        int vrow = dt*16 + lr;
        bf16x8 vf = *(const bf16x8*)&Vs[vrow*64 + (((kk*4 + lg) ^ (vrow & 7)))*8];
        o[dt] = MFMA16(pa, vf, o[dt]);
      }
    }
  }

  lst += __shfl_xor(lst, 16);
  lst += __shfl_xor(lst, 32);
  #pragma unroll
  for (int r = 0; r < 4; ++r){
    float l = __shfl(lst, lg*4 + r);
    float inv = 1.0f / l;
    int qg = qw + lg*4 + r;
    u16* op = ob + (size_t)(b*4096 + qg)*2048 + h*128;
    #pragma unroll
    for (int dt = 0; dt < 8; ++dt)
      op[dt*16 + lr] = f2bf(o[dt][r] * inv);
  }
}

// ---------------- launch ----------------
extern "C" void kernel_launch(void* const* d_in, const int* in_sizes, int n_in,
                              void* d_out, int out_size, void* d_ws, size_t ws_size,
                              hipStream_t stream)
{
  const float* x  = (const float*)d_in[0];
  const float* wq = (const float*)d_in[1];
  const float* wk = (const float*)d_in[2];
  const float* wv = (const float*)d_in[3];
  const float* wo = (const float*)d_in[4];
  float* outp = (float*)d_out;
  char* ws = (char*)d_ws;

  u16* xb    = (u16*)(ws);                  // bf16 x; reused as attn out
  u16* ob    = xb;
  u16* qbuf  = (u16*)(ws + 33554432u);
  u16* kbuf  = (u16*)(ws + 67108864u);
  u16* vtb   = (u16*)(ws + 75497472u);
  u16* wqkvb = (u16*)(ws + 83886080u);
  u16* wob   = (u16*)(ws + 96468992u);
  float* ct  = (float*)(ws + 104857600u);
  float* st  = (float*)(ws + 105906176u);

  hipFuncSetAttribute(reinterpret_cast<const void*>(&k_gemm8<192,1>),
                      hipFuncAttributeMaxDynamicSharedMemorySize, 114688);
  hipFuncSetAttribute(reinterpret_cast<const void*>(&k_gemm8<256,0>),
                      hipFuncAttributeMaxDynamicSharedMemorySize, 131072);

  k_convert<<<2048, 256, 0, stream>>>(x,  xb,            4194304);
  k_convert<<<2048, 256, 0, stream>>>(wq, wqkvb,         1048576);
  k_convert<<<1024, 256, 0, stream>>>(wk, wqkvb+4194304,  262144);
  k_convert<<<1024, 256, 0, stream>>>(wv, wqkvb+5242880,  262144);
  k_convert<<<2048, 256, 0, stream>>>(wo, wob,           1048576);
  k_rope_table<<<1024, 256, 0, stream>>>(ct, st);

  dim3 g1(8192/256, 3072/192);   // 32 x 16 = 512 blocks: even 2 rounds
  k_gemm8<192,1><<<g1, 512, 114688, stream>>>(xb, wqkvb, nullptr, qbuf, kbuf, vtb,
                                              ct, st, 8192, 3072, 2048);

  k_attn<<<1024, 512, 0, stream>>>(qbuf, kbuf, vtb, ob);

  dim3 g2(8192/256, 2048/256);   // 32 x 8 = 256 blocks: even 1 round
  k_gemm8<256,0><<<g2, 512, 131072, stream>>>(ob, wob, outp, nullptr, nullptr, nullptr,
                                              ct, st, 8192, 2048, 2048);
}